// Round 11
// baseline (239.456 us; speedup 1.0000x reference)
//
#include <hip/hip_runtime.h>
#include <hip/hip_bf16.h>

#define BB 2
#define SS 2048
#define NH 32
#define NKV 8
#define GQ (NH / NKV)
#define DD 128
#define QBLK 128
#define KVBLK 64
#define NQT (SS / QBLK)
#define NTHREADS 512

// +8 shorts (16B) padding on LDS leading dims (R10: conflicts 9.4e7 -> 1.8e7).
#define KPAD (DD + 8)
#define VPAD (KVBLK + 8)

typedef __bf16 bf16x8 __attribute__((ext_vector_type(8)));
typedef short short8 __attribute__((ext_vector_type(8)));
typedef float f32x4 __attribute__((ext_vector_type(4)));
typedef unsigned int u32x4 __attribute__((ext_vector_type(4)));

__device__ inline bf16x8 cvt_bf16x8(float4 a, float4 b) {
  bf16x8 r;
  r[0] = (__bf16)a.x; r[1] = (__bf16)a.y; r[2] = (__bf16)a.z; r[3] = (__bf16)a.w;
  r[4] = (__bf16)b.x; r[5] = (__bf16)b.y; r[6] = (__bf16)b.z; r[7] = (__bf16)b.w;
  return r;
}

// Barrier that does NOT drain vmcnt: each wave drains its own DS ops
// (lgkmcnt) then syncs. Prefetch global loads stay in flight across it.
__device__ inline void lds_barrier() {
  asm volatile("s_waitcnt lgkmcnt(0)" ::: "memory");
  __builtin_amdgcn_s_barrier();
}

__global__ __launch_bounds__(NTHREADS, 2)
void attn_mfma_pf(const float* __restrict__ qp, const float* __restrict__ kp,
                  const float* __restrict__ vp, float* __restrict__ op)
{
  __shared__ __align__(16) short kpl[KVBLK][KPAD];
  __shared__ __align__(16) short vtp[DD][VPAD];
  __shared__ __align__(16) short ppl[8][16][VPAD];

  const int tid  = threadIdx.x;
  const int wave = tid >> 6;
  const int lane = tid & 63;
  const int lhi  = lane >> 4;
  const int llo  = lane & 15;

  const int bid = blockIdx.x;
  const int bh  = bid % (BB * NH);
  const int qt  = NQT - 1 - bid / (BB * NH);   // heavy q-tiles first
  const int b   = bh / NH;
  const int h   = bh % NH;
  const int kh  = h / GQ;

  const int q0 = qt * QBLK;
  const int qw = q0 + wave * 16;

  const float scale = 0.08838834764831845f;    // 1/sqrt(128)

  // ---- Q fragments in registers ----
  bf16x8 qf[4];
  {
    const float* qrow = qp + (((size_t)b * SS + (qw + llo)) * NH + h) * DD;
    #pragma unroll
    for (int kc = 0; kc < 4; ++kc) {
      const int d0 = kc * 32 + lhi * 8;
      float4 a = *(const float4*)(qrow + d0);
      float4 c = *(const float4*)(qrow + d0 + 4);
      a.x *= scale; a.y *= scale; a.z *= scale; a.w *= scale;
      c.x *= scale; c.y *= scale; c.z *= scale; c.w *= scale;
      qf[kc] = cvt_bf16x8(a, c);
    }
  }

  f32x4 oacc[8];
  #pragma unroll
  for (int f = 0; f < 8; ++f) oacc[f] = (f32x4){0.f, 0.f, 0.f, 0.f};
  float m_i[4], l_i[4];
  #pragma unroll
  for (int j = 0; j < 4; ++j) { m_i[j] = -1e30f; l_i[j] = 0.f; }

  const int ntiles = q0 / KVBLK + 2;

  // ---- per-thread staging addresses (tile 0); stride per tile is fixed ----
  const size_t tstep = (size_t)KVBLK * NKV * DD;   // 65536 floats
  const float* kbase[2];
  const float* vbase[2];
  #pragma unroll
  for (int it = 0; it < 2; ++it) {
    const int c = tid + it * NTHREADS;             // 0..1023
    kbase[it] = kp + (((size_t)b * SS + (c >> 4)) * NKV + kh) * DD + (c & 15) * 8;
    vbase[it] = vp + (((size_t)b * SS + (c & 63)) * NKV + kh) * DD + (c >> 6) * 8;
  }

  // ---- prologue: issue loads for tile 0 ----
  float4 kld[2][2], vld[2][2];
  #pragma unroll
  for (int it = 0; it < 2; ++it) {
    kld[it][0] = *(const float4*)(kbase[it]);
    kld[it][1] = *(const float4*)(kbase[it] + 4);
    vld[it][0] = *(const float4*)(vbase[it]);
    vld[it][1] = *(const float4*)(vbase[it] + 4);
  }

  for (int t = 0; t < ntiles; ++t) {
    const int t0 = t * KVBLK;
    lds_barrier();   // all waves done reading previous tile's LDS

    // ---- write tile t from regs to LDS (fp32->bf16 here) ----
    #pragma unroll
    for (int it = 0; it < 2; ++it) {
      const int c = tid + it * NTHREADS;
      *(u32x4*)&kpl[c >> 4][(c & 15) * 8] =
          __builtin_bit_cast(u32x4, cvt_bf16x8(kld[it][0], kld[it][1]));
      short8 es = __builtin_bit_cast(short8, cvt_bf16x8(vld[it][0], vld[it][1]));
      const int dg = c >> 6, tt = c & 63;
      #pragma unroll
      for (int j = 0; j < 8; ++j) vtp[dg * 8 + j][tt] = es[j];
    }

    // ---- issue prefetch for tile t+1 (stays in flight through compute) ----
    if (t + 1 < ntiles) {
      #pragma unroll
      for (int it = 0; it < 2; ++it) {
        const float* ks = kbase[it] + (size_t)(t + 1) * tstep;
        const float* vs = vbase[it] + (size_t)(t + 1) * tstep;
        kld[it][0] = *(const float4*)ks;
        kld[it][1] = *(const float4*)(ks + 4);
        vld[it][0] = *(const float4*)vs;
        vld[it][1] = *(const float4*)(vs + 4);
      }
    }
    __builtin_amdgcn_sched_barrier(0);   // pin prefetch issue above barrier
    lds_barrier();   // tile t's LDS visible to all waves; vmcnt NOT drained

    if (t0 > qw + 15) continue;   // wave-uniform skip (barriers still uniform)

    // ---- QK^T: S[16 q][64 t], 4 col-chunk MFMAs ----
    f32x4 sfrag[4];
    #pragma unroll
    for (int cc = 0; cc < 4; ++cc) {
      f32x4 acc = (f32x4){0.f, 0.f, 0.f, 0.f};
      const int r = cc * 16 + llo;             // K row for B-fragment
      #pragma unroll
      for (int kc = 0; kc < 4; ++kc) {
        u32x4 kb = *(const u32x4*)&kpl[r][(kc * 4 + lhi) * 8];
        acc = __builtin_amdgcn_mfma_f32_16x16x32_bf16(
                  qf[kc], __builtin_bit_cast(bf16x8, kb), acc, 0, 0, 0);
      }
      sfrag[cc] = acc;
    }

    // ---- causal mask ----
    if (t0 + KVBLK - 1 > qw) {
      #pragma unroll
      for (int cc = 0; cc < 4; ++cc)
        #pragma unroll
        for (int j = 0; j < 4; ++j) {
          const int tg = t0 + cc * 16 + llo;
          const int qg = qw + lhi * 4 + j;
          if (tg > qg) sfrag[cc][j] = -1e30f;
        }
    }

    // ---- online softmax (16-lane column groups) ----
    #pragma unroll
    for (int j = 0; j < 4; ++j) {
      float mx = fmaxf(fmaxf(sfrag[0][j], sfrag[1][j]), fmaxf(sfrag[2][j], sfrag[3][j]));
      #pragma unroll
      for (int off = 1; off < 16; off <<= 1)
        mx = fmaxf(mx, __shfl_xor(mx, off));
      const float mnew = fmaxf(m_i[j], mx);
      const float corr = __expf(m_i[j] - mnew);
      m_i[j] = mnew;
      float s = 0.f;
      #pragma unroll
      for (int cc = 0; cc < 4; ++cc) {
        const float p = __expf(sfrag[cc][j] - mnew);
        sfrag[cc][j] = p;
        s += p;
      }
      #pragma unroll
      for (int off = 1; off < 16; off <<= 1)
        s += __shfl_xor(s, off);
      l_i[j] = l_i[j] * corr + s;
      #pragma unroll
      for (int f = 0; f < 8; ++f) oacc[f][j] *= corr;
    }

    // ---- P -> per-wave LDS (scalar bf16 stores) ----
    #pragma unroll
    for (int cc = 0; cc < 4; ++cc)
      #pragma unroll
      for (int j = 0; j < 4; ++j)
        ppl[wave][lhi * 4 + j][cc * 16 + llo] =
            __builtin_bit_cast(short, (__bf16)sfrag[cc][j]);

    asm volatile("s_waitcnt lgkmcnt(0)" ::: "memory");
    __builtin_amdgcn_sched_barrier(0);

    // ---- PV: O[16 q][128 d] += P[16][64] * V[64][128] ----
    #pragma unroll
    for (int kc2 = 0; kc2 < 2; ++kc2) {
      u32x4 pa = *(const u32x4*)&ppl[wave][llo][(kc2 * 4 + lhi) * 8];
      #pragma unroll
      for (int f = 0; f < 8; ++f) {
        u32x4 vb = *(const u32x4*)&vtp[f * 16 + llo][(kc2 * 4 + lhi) * 8];
        oacc[f] = __builtin_amdgcn_mfma_f32_16x16x32_bf16(
                      __builtin_bit_cast(bf16x8, pa),
                      __builtin_bit_cast(bf16x8, vb), oacc[f], 0, 0, 0);
      }
    }
  }

  // ---- epilogue: O / l ----
  #pragma unroll
  for (int j = 0; j < 4; ++j) {
    const float inv = 1.f / l_i[j];
    const int qg = qw + lhi * 4 + j;
    float* orow = op + (((size_t)b * SS + qg) * NH + h) * DD;
    #pragma unroll
    for (int f = 0; f < 8; ++f)
      orow[f * 16 + llo] = oacc[f][j] * inv;
  }
}

extern "C" void kernel_launch(void* const* d_in, const int* in_sizes, int n_in,
                              void* d_out, int out_size, void* d_ws, size_t ws_size,
                              hipStream_t stream) {
  const float* q = (const float*)d_in[0];
  const float* k = (const float*)d_in[1];
  const float* v = (const float*)d_in[2];
  float* out = (float*)d_out;
  dim3 grid(BB * NH * NQT);
  dim3 block(NTHREADS);
  attn_mfma_pf<<<grid, block, 0, stream>>>(q, k, v, out);
}